// Round 8
// baseline (369.280 us; speedup 1.0000x reference)
//
#include <hip/hip_runtime.h>

typedef _Float16 half8    __attribute__((ext_vector_type(8)));
typedef float    floatx16 __attribute__((ext_vector_type(16)));
typedef float    float4v  __attribute__((ext_vector_type(4)));

#define K_DIM 256
#define N_DIM 256
#define NBLK  4096    // 4096 blocks * 4 waves * 32 rows = 524288 rows

// Build W^T in f16 bit patterns: W[k][n] = 2^shift[k][n] * (-1)^sign[k][n].
// shift is an exact integer in [-10,-1]; 2^shift is exact in f16.
// (Proven mechanism: rounds 2-6 all validated this build + cross-kernel read.)
__global__ __launch_bounds__(256) void build_wT(const float* __restrict__ shift,
                                                const float* __restrict__ sgn,
                                                unsigned short* __restrict__ wT) {
    int idx = blockIdx.x * 256 + threadIdx.x;   // idx = k*256 + n
    int k = idx >> 8, n = idx & 255;
    float sh = shift[idx];
    float sg = sgn[idx];
    int e = 15 + (int)sh;                       // f16 exponent field, 5..14
    unsigned short wv = (unsigned short)(((sg != 0.0f) ? 0x8000 : 0) | (e << 10));
    wT[n * 256 + k] = wv;                       // W^T[n][k], contiguous K
}

// Barrier-free, LDS-free, race-free-by-construction streaming GEMM.
// Per wave: bulk-issue ALL A loads (32 KB in flight), cvt, MFMA against
// B loaded directly from the L2-resident 128 KB W^T, store everything last.
__global__ __launch_bounds__(256, 2) void dense_shift_gemm(
        const float* __restrict__ x,
        const unsigned short* __restrict__ wT,
        const float* __restrict__ bias,
        float* __restrict__ out) {

    const int t  = threadIdx.x;
    const int l  = t & 63;
    const int ln = l & 31;
    const int hi = l >> 5;

    const long row0 = ((long)blockIdx.x * 4 + (t >> 6)) * 32;   // wave's 32 rows

    // ---- bias first: oldest in the vmcnt FIFO, drained for free by the
    // first A-wait (L2-hot) ----
    float bv[8];
#pragma unroll
    for (int nb = 0; nb < 8; ++nb) bv[nb] = bias[nb * 32 + ln];

    // ---- A: issue the ENTIRE strip up front (32 x dwordx4 = 512 B/lane =
    // 32 KB/wave in flight; 40 vmem ops incl. bias < vmcnt cap 63) ----
    // A layout for mfma_f32_32x32x16_f16: row = l&31, k = (l>>5)*8 + j.
    const float* ax = x + (row0 + ln) * (long)K_DIM + hi * 8;
    float4v F[32];
#pragma unroll
    for (int ks = 0; ks < 16; ++ks) {
        F[2 * ks]     = *(const float4v*)(ax + ks * 16);
        F[2 * ks + 1] = *(const float4v*)(ax + ks * 16 + 4);
    }
    __builtin_amdgcn_sched_barrier(0);   // pin: all loads issued before any cvt

    // ---- cvt f32 -> f16 (consumed in issue order -> progressive vmcnt(N)
    // waits; F dies as a16 is born) ----
    half8 a16[16];
#pragma unroll
    for (int ks = 0; ks < 16; ++ks) {
        float4v f0 = F[2 * ks], f1 = F[2 * ks + 1];
        half8 a;
        a[0] = (_Float16)f0[0]; a[1] = (_Float16)f0[1];
        a[2] = (_Float16)f0[2]; a[3] = (_Float16)f0[3];
        a[4] = (_Float16)f1[0]; a[5] = (_Float16)f1[1];
        a[6] = (_Float16)f1[2]; a[7] = (_Float16)f1[3];
        a16[ks] = a;
    }

    // ---- accumulators, bias pre-folded ----
    floatx16 acc[8];
#pragma unroll
    for (int nb = 0; nb < 8; ++nb)
#pragma unroll
        for (int r = 0; r < 16; ++r) acc[nb][r] = bv[nb];

    // ---- MFMA: B straight from L2-hot W^T (B layout: col = l&31,
    // k = (l>>5)*8 + j). 8 independent acc chains per ks slice -> full ILP;
    // compiler pipelines next slice's 8 B-loads under this slice's MFMAs. ----
    const unsigned short* bx = wT + ln * K_DIM + hi * 8;
#pragma unroll
    for (int ks = 0; ks < 16; ++ks) {
#pragma unroll
        for (int nb = 0; nb < 8; ++nb) {
            half8 b = *(const half8*)(bx + nb * 32 * K_DIM + ks * 16);
            acc[nb] = __builtin_amdgcn_mfma_f32_32x32x16_f16(a16[ks], b, acc[nb], 0, 0, 0);
        }
    }

    // ---- stores last (nothing ever waits on them inside this wave).
    // C layout: col = l&31, row = (r&3) + 8*(r>>2) + 4*(l>>5). ----
    float* op = out + (row0 + 4 * hi) * (long)N_DIM + ln;
#pragma unroll
    for (int nb = 0; nb < 8; ++nb) {
#pragma unroll
        for (int r = 0; r < 16; ++r) {
            const int row = (r & 3) + 8 * (r >> 2);
            op[(long)row * N_DIM + nb * 32] = acc[nb][r];
        }
    }
}

extern "C" void kernel_launch(void* const* d_in, const int* in_sizes, int n_in,
                              void* d_out, int out_size, void* d_ws, size_t ws_size,
                              hipStream_t stream) {
    const float* x     = (const float*)d_in[0];
    const float* shift = (const float*)d_in[1];
    const float* sgn   = (const float*)d_in[2];
    const float* bias  = (const float*)d_in[3];
    float* out = (float*)d_out;
    unsigned short* wT = (unsigned short*)d_ws;   // 256*256*2 = 128 KB scratch

    build_wT<<<256, 256, 0, stream>>>(shift, sgn, wT);

    dense_shift_gemm<<<NBLK, 256, 0, stream>>>(x, wT, bias, out);
}

// Round 9
// 218.641 us; speedup vs baseline: 1.6890x; 1.6890x over previous
//
#include <hip/hip_runtime.h>

typedef _Float16     half8    __attribute__((ext_vector_type(8)));
typedef float        floatx16 __attribute__((ext_vector_type(16)));
typedef float        float4v  __attribute__((ext_vector_type(4)));
typedef unsigned int uint2v   __attribute__((ext_vector_type(2)));
typedef unsigned int uint4v   __attribute__((ext_vector_type(4)));

#define K_DIM 256
#define N_DIM 256
#define NBLK  2048    // 2048 blocks * 8 waves * 32 rows = 524288 rows

typedef const __attribute__((address_space(1))) void global_cv_t;
typedef __attribute__((address_space(3))) void lds_v_t;

// W^T in bf8 (e5m2), PLAIN layout wT8[n*256+k]. EXACT: W = +-2^e, e in [-10,-1]
// -> e5m2 normal (exp field 5..14, mantissa 0); bf8->f16 is byte<<8 (exact).
__global__ __launch_bounds__(256) void build_wT8(const float* __restrict__ shift,
                                                 const float* __restrict__ sgn,
                                                 unsigned char* __restrict__ wT8) {
    int idx = blockIdx.x * 256 + threadIdx.x;   // idx = n*256 + k
    int n = idx >> 8, k = idx & 255;
    float sh = shift[k * 256 + n];
    float sg = sgn[k * 256 + n];
    int e = 15 + (int)sh;                       // e5m2 exponent field, 5..14
    wT8[idx] = (unsigned char)(((sg != 0.0f) ? 0x80 : 0) | (e << 2));
}

// FIFO-hygienic streaming GEMM:
//  - vmcnt domain = A-DMA only (B lives in LDS/lgkm; stores issued dead-last)
//  - one barrier total (B init); afterwards each wave reads ONLY LDS it DMA'd
//    itself -> per-wave vmcnt waits are the only synchronization; waves free-run.
__global__ __launch_bounds__(512, 2) void dense_shift_gemm(
        const float* __restrict__ x,
        const unsigned char* __restrict__ wT8,
        const float* __restrict__ bias,
        float* __restrict__ out) {

    // [0, 64K):  B bf8. Row n (256 B = 16 slots): phys slot s holds logical s^(n&15).
    // [64K,128K): per-wave A f32, 2 buffers of [32 rows][128 B]; phys slot s of
    //             row r holds logical s^(r&7). Both swizzles applied on the DMA
    //             SOURCE address (dest must stay linear: base + lane*16).
    __shared__ __align__(16) unsigned char lds[131072];

    const int t  = threadIdx.x;
    const int w  = t >> 6;            // wave 0..7
    const int l  = t & 63;
    const int ln = l & 31;
    const int hi = l >> 5;

    const long row0 = ((long)blockIdx.x * 8 + w) * 32;   // wave's 32 rows

    // bias first: oldest in FIFO, drained by the prologue vmcnt(0)
    float bv[8];
#pragma unroll
    for (int nb = 0; nb < 8; ++nb) bv[nb] = bias[nb * 32 + ln];

    // ---- B DMA: 8 instrs/wave, 4 rows each; source slot pre-XOR'd by n&15 ----
    {
        const int nL  = l >> 4;       // row within quad
        const int t16 = l & 15;       // dest slot
#pragma unroll
        for (int i = 0; i < 8; ++i) {
            const int n = w * 32 + i * 4 + nL;
            const unsigned char* g = wT8 + n * 256 + ((t16 ^ (n & 15)) << 4);
            __builtin_amdgcn_global_load_lds(
                (global_cv_t*)g,
                (lds_v_t*)(lds + (w * 32 + i * 4) * 256), 16, 0, 0);
        }
    }

    // ---- A DMA geometry: instr q covers rows q*8 + (l>>3), slot l&7;
    //      source slot pre-XOR'd by row&7 ----
    const int arow  = l >> 3;                 // 0..7
    const int aslot = l & 7;
    const float* axg = x + (row0 + arow) * (long)K_DIM + (aslot ^ arow) * 4;
    char* aw = (char*)lds + 65536 + w * 8192;

#define ADMA(c_, buf_) do {                                                  \
        _Pragma("unroll")                                                    \
        for (int q = 0; q < 4; ++q) {                                        \
            __builtin_amdgcn_global_load_lds(                                \
                (global_cv_t*)(axg + q * 8 * K_DIM + (c_) * 32),             \
                (lds_v_t*)(aw + (buf_) * 4096 + q * 1024), 16, 0, 0);        \
        }                                                                    \
    } while (0)

    ADMA(0, 0);
    ADMA(1, 1);

    asm volatile("s_waitcnt vmcnt(0)" ::: "memory");   // explicit: all DMA landed
    __syncthreads();                                   // the ONLY barrier (B ready)

    floatx16 acc[8];
#pragma unroll
    for (int nb = 0; nb < 8; ++nb)
#pragma unroll
        for (int r = 0; r < 16; ++r) acc[nb][r] = bv[nb];   // bias pre-folded

    const char* bl    = (const char*)lds;
    const int   sx7   = ln & 7;
    const int   sx15  = ln & 15;
    const char* arp   = aw + ln * 128;        // this lane's A row (+ buf*4096)

#define WAITV(n_) do {                                                       \
        asm volatile("s_waitcnt vmcnt(" #n_ ")" ::: "memory");               \
        __builtin_amdgcn_sched_barrier(0);                                   \
    } while (0)

    // One K=32 chunk: A from own LDS buffer (free-2-way swizzled b128 reads),
    // cvt to f16, THEN overwrite-DMA for chunk i_+2, then B (b64 + exact
    // bf8->f16 unpack) and 16 MFMA.
#define CHUNK(i_, buf_, DMAI) do {                                           \
        const char* ab_ = arp + (buf_) * 4096;                               \
        float4v f00 = *(const float4v*)(ab_ + (((hi * 2    ) ^ sx7) << 4));  \
        float4v f01 = *(const float4v*)(ab_ + (((hi * 2 + 1) ^ sx7) << 4));  \
        float4v f10 = *(const float4v*)(ab_ + (((4 + hi * 2    ) ^ sx7) << 4));\
        float4v f11 = *(const float4v*)(ab_ + (((4 + hi * 2 + 1) ^ sx7) << 4));\
        half8 a0, a1;                                                        \
        a0[0]=(_Float16)f00[0]; a0[1]=(_Float16)f00[1];                      \
        a0[2]=(_Float16)f00[2]; a0[3]=(_Float16)f00[3];                      \
        a0[4]=(_Float16)f01[0]; a0[5]=(_Float16)f01[1];                      \
        a0[6]=(_Float16)f01[2]; a0[7]=(_Float16)f01[3];                      \
        a1[0]=(_Float16)f10[0]; a1[1]=(_Float16)f10[1];                      \
        a1[2]=(_Float16)f10[2]; a1[3]=(_Float16)f10[3];                      \
        a1[4]=(_Float16)f11[0]; a1[5]=(_Float16)f11[1];                      \
        a1[6]=(_Float16)f11[2]; a1[7]=(_Float16)f11[3];                      \
        __builtin_amdgcn_sched_barrier(0);                                   \
        DMAI;                                                                \
        __builtin_amdgcn_sched_barrier(0);                                   \
        _Pragma("unroll")                                                    \
        for (int ks = 0; ks < 2; ++ks) {                                     \
            _Pragma("unroll")                                                \
            for (int nb = 0; nb < 8; ++nb) {                                 \
                uint2v d = *(const uint2v*)(bl + (nb * 32 + ln) * 256        \
                             + ((((i_) * 2 + ks) ^ sx15) << 4) + hi * 8);    \
                unsigned q0 = ((d[0] & 0x000000FFu) << 8)  | ((d[0] & 0x0000FF00u) << 16); \
                unsigned q1 = ((d[0] & 0x00FF0000u) >> 8)  |  (d[0] & 0xFF000000u);        \
                unsigned q2 = ((d[1] & 0x000000FFu) << 8)  | ((d[1] & 0x0000FF00u) << 16); \
                unsigned q3 = ((d[1] & 0x00FF0000u) >> 8)  |  (d[1] & 0xFF000000u);        \
                uint4v qq = {q0, q1, q2, q3};                                \
                half8 b = __builtin_bit_cast(half8, qq);                     \
                acc[nb] = __builtin_amdgcn_mfma_f32_32x32x16_f16(            \
                              ks ? a1 : a0, b, acc[nb], 0, 0, 0);            \
            }                                                                \
        }                                                                    \
    } while (0)

    // 8 chunks; chunk c lives in buf c&1; DMA(c+2) issued only after chunk c's
    // cvt consumed the buffer it overwrites. vmcnt(4) allows the NEXT chunk's
    // DMA to stay in flight; only iter 7 fully drains.
    /* i=0: chunks 0,1 drained by prologue */ CHUNK(0, 0, ADMA(2, 0));
    WAITV(4);  CHUNK(1, 1, ADMA(3, 1));
    WAITV(4);  CHUNK(2, 0, ADMA(4, 0));
    WAITV(4);  CHUNK(3, 1, ADMA(5, 1));
    WAITV(4);  CHUNK(4, 0, ADMA(6, 0));
    WAITV(4);  CHUNK(5, 1, ADMA(7, 1));
    WAITV(4);  CHUNK(6, 0, (void)0);
    WAITV(0);  CHUNK(7, 1, (void)0);

#undef ADMA
#undef WAITV
#undef CHUNK

    // ---- stores dead-last: nothing ever waits on them.
    // C layout: col = l&31, row = (r&3) + 8*(r>>2) + 4*(l>>5). ----
    float* op = out + (row0 + 4 * hi) * (long)N_DIM + ln;
#pragma unroll
    for (int nb = 0; nb < 8; ++nb) {
#pragma unroll
        for (int r = 0; r < 16; ++r) {
            const int row = (r & 3) + 8 * (r >> 2);
            op[(long)row * N_DIM + nb * 32] = acc[nb][r];
        }
    }
}

extern "C" void kernel_launch(void* const* d_in, const int* in_sizes, int n_in,
                              void* d_out, int out_size, void* d_ws, size_t ws_size,
                              hipStream_t stream) {
    const float* x     = (const float*)d_in[0];
    const float* shift = (const float*)d_in[1];
    const float* sgn   = (const float*)d_in[2];
    const float* bias  = (const float*)d_in[3];
    float* out = (float*)d_out;
    unsigned char* wT8 = (unsigned char*)d_ws;   // 256*256 = 64 KB scratch

    build_wT8<<<256, 256, 0, stream>>>(shift, sgn, wT8);

    dense_shift_gemm<<<NBLK, 512, 0, stream>>>(x, wT8, bias, out);
}